// Round 5
// baseline (151.578 us; speedup 1.0000x reference)
//
#include <hip/hip_runtime.h>
#include <math.h>

typedef _Float16 half8  __attribute__((ext_vector_type(8)));
typedef _Float16 half4v __attribute__((ext_vector_type(4)));
typedef _Float16 half2v __attribute__((ext_vector_type(2)));
typedef float    f32x4  __attribute__((ext_vector_type(4)));
typedef float    f32x2  __attribute__((ext_vector_type(2)));
typedef float    f32x16 __attribute__((ext_vector_type(16)));
typedef int      int2v  __attribute__((ext_vector_type(2)));
typedef int      int4v  __attribute__((ext_vector_type(4)));

// swizzled-weight offsets in halfs inside d_ws (32x32x16 fragment layout)
#define W1OFF 0        // 8 MT-tiles * 64 lanes * 8 = 4096 halfs (K padded 2->16)
#define W2OFF 4096     // 16 kk * 8 MT * 64 * 8 = 65536
#define W3OFF 69632    // 65536
#define W4OFF 135168   // 16x16 frags: 8 kkb * 64 * 8 = 4096 (N padded 3->16)
#define SWTOT 139264
#define OUT_PIX (16*128*128)

// ---------------- prep: swizzle weights (fp32 -> f16 frag-contiguous) + dx/dy tail ----
// 32x32x16 A-frag: lane holds A[m = MT*32 + (lane&31)][k = kk*16 + (lane>>5)*8 + j]
__global__ void inr_prep(const float* __restrict__ W1, const float* __restrict__ W2,
                         const float* __restrict__ W3, const float* __restrict__ W4,
                         const int* __restrict__ sidx, const float* __restrict__ sv,
                         _Float16* __restrict__ wsw, float* __restrict__ outtail)
{
    int tid = blockIdx.x * 256 + threadIdx.x;
    if (tid < 16) {
        int si = sidx[tid];
        outtail[tid]      = sv[2*si + 1];   // dx = shift[:,1]
        outtail[16 + tid] = sv[2*si + 0];   // dy = shift[:,0]
    }
    if (tid >= SWTOT) return;
    int kind, rel;
    if      (tid < W2OFF) { kind = 0; rel = tid; }
    else if (tid < W3OFF) { kind = 1; rel = tid - W2OFF; }
    else if (tid < W4OFF) { kind = 2; rel = tid - W3OFF; }
    else                  { kind = 3; rel = tid - W4OFF; }
    int j    = rel & 7;
    int lane = (rel >> 3) & 63;
    int blk  = rel >> 9;
    float val;
    if (kind == 3) {                       // W4 (16x16 frag): A[m][k] = W4[k][m], m<3 else 0
        int q = lane >> 4, ln = lane & 15;
        int m = ln;
        int k = blk * 32 + q * 8 + j;
        val = (m < 3) ? W4[k*3 + m] : 0.0f;
    } else {
        int hi = lane >> 5, lo = lane & 31;
        if (kind == 0) {                   // W1: one kk (K padded 2->16), blk = MT
            int m = blk*32 + lo;
            int k = hi*8 + j;
            val = (k < 2) ? W1[k*256 + m] : 0.0f;
        } else {                           // W2/W3: blk = kk*8 + MT
            int MT = blk & 7, kk = blk >> 3;
            int m = MT*32 + lo;
            int k = kk*16 + hi*8 + j;
            val = (kind == 1) ? W2[k*256 + m] : W3[k*256 + m];
        }
    }
    wsw[tid] = (_Float16)val;
}

// ---------------- fused MLP: register-carried activations across layer boundaries ----
// LDS layout: hbuf[(hid>>3)*1024 + px*8 + (hid&7)]  (granule = 8 halfs, 128 px)
// acc[mt][nt] (32x32x16 C/D): lane(hi,lo) reg r = act[64w+32mt+(r&3)+8(r>>2)+4hi][32nt+lo]
// F[i][nt]   (next-layer B-frag kk=4w+i): lane(hi,lo) = act[64w+16i+8hi+j][32nt+lo]
// Built from acc via 2x permlane32_swap per frag (hi-half exchange); same half8 is
// the ds_write payload (granule 8w+2i+hi, px-contiguous b128, conflict-free).

__device__ __forceinline__ int pack_relu(float a, float b)
{
    half2v hp;
    hp[0] = (_Float16)fmaxf(a, 0.f);
    hp[1] = (_Float16)fmaxf(b, 0.f);
    return __builtin_bit_cast(int, hp);
}

__device__ __forceinline__ void make_frags(const f32x16 (&acc)[2][4], half8 (&F)[4][4])
{
#pragma unroll
    for (int i = 0; i < 4; ++i) {
        int ms = i >> 1, e = i & 1;
#pragma unroll
        for (int nt = 0; nt < 4; ++nt) {
            int w0 = pack_relu(acc[ms][nt][8*e+0], acc[ms][nt][8*e+1]);
            int w1 = pack_relu(acc[ms][nt][8*e+2], acc[ms][nt][8*e+3]);
            int w2 = pack_relu(acc[ms][nt][8*e+4], acc[ms][nt][8*e+5]);
            int w3 = pack_relu(acc[ms][nt][8*e+6], acc[ms][nt][8*e+7]);
            int2v r02 = __builtin_amdgcn_permlane32_swap(w0, w2, false, false);
            int2v r13 = __builtin_amdgcn_permlane32_swap(w1, w3, false, false);
            int4v fw;
            fw[0] = r02[0];   // j0,j1
            fw[1] = r13[0];   // j2,j3
            fw[2] = r02[1];   // j4,j5
            fw[3] = r13[1];   // j6,j7
            F[i][nt] = __builtin_bit_cast(half8, fw);
        }
    }
}

// acc[mt][nt][4m+c] = bias[64w + 32mt + 8m + 4hi + c]
__device__ __forceinline__ void bias_init(f32x16 (&acc)[2][4], const float* __restrict__ bias,
                                          int w, int hi)
{
#pragma unroll
    for (int mt = 0; mt < 2; ++mt)
#pragma unroll
        for (int m = 0; m < 4; ++m) {
            f32x4 bv = *(const f32x4*)&bias[64*w + 32*mt + 8*m + 4*hi];
#pragma unroll
            for (int nt = 0; nt < 4; ++nt)
#pragma unroll
                for (int c = 0; c < 4; ++c)
                    acc[mt][nt][4*m+c] = bv[c];
        }
}

// phase 1: own 4 kk entirely from register fragments (no LDS reads, no barrier dep)
__device__ __forceinline__ void phase1(const half8* __restrict__ Asw,
                                       f32x16 (&acc)[2][4], const half8 (&F)[4][4],
                                       int w, int lane)
{
#pragma unroll
    for (int i = 0; i < 4; ++i) {
        int kk = 4*w + i;
        half8 aw[2];
#pragma unroll
        for (int mt = 0; mt < 2; ++mt)
            aw[mt] = Asw[(kk*8 + 2*w + mt)*64 + lane];
#pragma unroll
        for (int nt = 0; nt < 4; ++nt)
#pragma unroll
            for (int mt = 0; mt < 2; ++mt)
                acc[mt][nt] = __builtin_amdgcn_mfma_f32_32x32x16_f16(aw[mt], F[i][nt], acc[mt][nt], 0, 0, 0);
    }
}

// phase 2: remaining 12 kk from LDS (other waves' granules)
__device__ __forceinline__ void phase2(const half8* __restrict__ Asw,
                                       f32x16 (&acc)[2][4], const _Float16* __restrict__ hbuf,
                                       int w, int lane)
{
    int lo = lane & 31, hi = lane >> 5;
#pragma unroll
    for (int idx = 0; idx < 12; ++idx) {
        int kk = (4*w + 4 + idx) & 15;
        half8 aw[2];
#pragma unroll
        for (int mt = 0; mt < 2; ++mt)
            aw[mt] = Asw[(kk*8 + 2*w + mt)*64 + lane];
        half8 bf[4];
        int g = kk*2 + hi;
#pragma unroll
        for (int nt = 0; nt < 4; ++nt)
            bf[nt] = *(const half8*)&hbuf[g*1024 + (32*nt + lo)*8];
#pragma unroll
        for (int nt = 0; nt < 4; ++nt)
#pragma unroll
            for (int mt = 0; mt < 2; ++mt)
                acc[mt][nt] = __builtin_amdgcn_mfma_f32_32x32x16_f16(aw[mt], bf[nt], acc[mt][nt], 0, 0, 0);
    }
}

// write F to own granules: 16x ds_write_b128, conflict-free (stride-16B per lane)
__device__ __forceinline__ void write_frags(_Float16* hbuf, const half8 (&F)[4][4],
                                            int w, int lane)
{
    int lo = lane & 31, hi = lane >> 5;
#pragma unroll
    for (int i = 0; i < 4; ++i)
#pragma unroll
        for (int nt = 0; nt < 4; ++nt)
            *(half8*)&hbuf[(8*w + 2*i + hi)*1024 + (32*nt + lo)*8] = F[i][nt];
}

__launch_bounds__(256, 2)
__global__ void inr_fused(const float* __restrict__ x, const int* __restrict__ sidx_p,
                          const float* __restrict__ sv, const float* __restrict__ ra,
                          const float* __restrict__ cs, const float* __restrict__ csh,
                          const float* __restrict__ b1, const float* __restrict__ b2,
                          const float* __restrict__ b3, const float* __restrict__ b4,
                          const _Float16* __restrict__ wsw, float* __restrict__ out)
{
    __shared__ __align__(16) _Float16 hbuf[32768];     // 128 px x 256 hid, 64 KB
    int t = threadIdx.x;
    int lane = t & 63, w = t >> 6, q = lane >> 4, ln = lane & 15;
    int lo = lane & 31, hi = lane >> 5;
    int pixbase = blockIdx.x * 128;
    int b = pixbase >> 14;                             // 16384 px per image
    int sidx = sidx_p[b];
    float dy = sv[2*sidx], dx = sv[2*sidx + 1];
    float ang = ra[sidx];
    float sn, cn;
    sincosf(ang, &sn, &cn);

    // stage coords: layer-1 K=16 -> granules 0,1 only; uv at hid 0,1
    if (t < 128) {
        int p = t;
        f32x2 xv = *(const f32x2*)&x[(pixbase + p)*2];
        float u = cn*xv[0] - sn*xv[1] + dx;
        float v = sn*xv[0] + cn*xv[1] + dy;
        half8 z;
#pragma unroll
        for (int i = 0; i < 8; ++i) z[i] = (_Float16)0.0f;
        z[0] = (_Float16)u; z[1] = (_Float16)v;
        *(half8*)&hbuf[0*1024 + p*8] = z;
    } else {
        int p = t - 128;
        half8 z;
#pragma unroll
        for (int i = 0; i < 8; ++i) z[i] = (_Float16)0.0f;
        *(half8*)&hbuf[1*1024 + p*8] = z;
    }
    __syncthreads();                                   // sync0: input staged

    const half8* wsw8 = (const half8*)wsw;
    f32x16 acc[2][4];
    half8 F[4][4];

    // ---- layer 1 (K=16 padded; reads granules 0,1) ----
    bias_init(acc, b1, w, hi);
    {
        half8 aw[2];
#pragma unroll
        for (int mt = 0; mt < 2; ++mt)
            aw[mt] = wsw8[(2*w + mt)*64 + lane];
        half8 bf[4];
#pragma unroll
        for (int nt = 0; nt < 4; ++nt)
            bf[nt] = *(const half8*)&hbuf[hi*1024 + (32*nt + lo)*8];
#pragma unroll
        for (int nt = 0; nt < 4; ++nt)
#pragma unroll
            for (int mt = 0; mt < 2; ++mt)
                acc[mt][nt] = __builtin_amdgcn_mfma_f32_32x32x16_f16(aw[mt], bf[nt], acc[mt][nt], 0, 0, 0);
    }
    make_frags(acc, F);                                // act1 fragments in regs
    __syncthreads();                                   // B1: all L1 reads of g0,g1 done

    // ---- layer 2 ----
    bias_init(acc, b2, w, hi);
    write_frags(hbuf, F, w, lane);                     // ds_write burst ...
    phase1(wsw8 + (W2OFF >> 3), acc, F, w, lane);      // ... overlapped with reg-MFMAs
    __syncthreads();                                   // A2: act1 fully in LDS
    phase2(wsw8 + (W2OFF >> 3), acc, hbuf, w, lane);
    make_frags(acc, F);                                // act2 fragments
    __syncthreads();                                   // B2: all phase-2 reads done

    // ---- layer 3 ----
    bias_init(acc, b3, w, hi);
    write_frags(hbuf, F, w, lane);
    phase1(wsw8 + (W3OFF >> 3), acc, F, w, lane);
    __syncthreads();                                   // A3
    phase2(wsw8 + (W3OFF >> 3), acc, hbuf, w, lane);
    make_frags(acc, F);                                // act3 fragments
    __syncthreads();                                   // B3

    write_frags(hbuf, F, w, lane);
    __syncthreads();                                   // A4: act3 fully in LDS

    // ---- layer 4: 16x16 (M=16, 3 real), each wave -> 32 pixels ----
    const half8* w4p = wsw8 + (W4OFF >> 3);
    f32x4 a4[2];
    a4[0] = (f32x4){0.f,0.f,0.f,0.f};
    a4[1] = (f32x4){0.f,0.f,0.f,0.f};
#pragma unroll
    for (int kkb = 0; kkb < 8; ++kkb) {
        half8 aw = w4p[kkb*64 + lane];
#pragma unroll
        for (int i = 0; i < 2; ++i) {
            int pixel = 16*(2*w + i) + ln;
            half8 bf = *(const half8*)&hbuf[(kkb*4 + q)*1024 + pixel*8];
            a4[i] = __builtin_amdgcn_mfma_f32_16x16x32_f16(aw, bf, a4[i], 0, 0, 0);
        }
    }
    if (q == 0) {                                      // rows 0..2 = output channels
        bool doc = (sidx != 0);
        float s0 = cs[sidx*3+0], s1 = cs[sidx*3+1], s2 = cs[sidx*3+2];
        float t0 = csh[sidx*3+0], t1 = csh[sidx*3+1], t2 = csh[sidx*3+2];
        float bb0 = b4[0], bb1 = b4[1], bb2 = b4[2];
#pragma unroll
        for (int i = 0; i < 2; ++i) {
            int gp = pixbase + 16*(2*w + i) + ln;
            float v0 = a4[i][0] + bb0;
            float v1 = a4[i][1] + bb1;
            float v2 = a4[i][2] + bb2;
            if (doc) { v0 = v0*s0 + t0; v1 = v1*s1 + t1; v2 = v2*s2 + t2; }
            out[gp*3 + 0] = v0;
            out[gp*3 + 1] = v1;
            out[gp*3 + 2] = v2;
        }
    }
}

extern "C" void kernel_launch(void* const* d_in, const int* in_sizes, int n_in,
                              void* d_out, int out_size, void* d_ws, size_t ws_size,
                              hipStream_t stream)
{
    const float* x    = (const float*)d_in[0];
    const int*   sidx = (const int*)  d_in[1];
    const float* sv   = (const float*)d_in[2];
    const float* ra   = (const float*)d_in[3];
    const float* cs   = (const float*)d_in[4];
    const float* csh  = (const float*)d_in[5];
    const float* W1   = (const float*)d_in[6];
    const float* b1   = (const float*)d_in[7];
    const float* W2   = (const float*)d_in[8];
    const float* b2   = (const float*)d_in[9];
    const float* W3   = (const float*)d_in[10];
    const float* b3   = (const float*)d_in[11];
    const float* W4   = (const float*)d_in[12];
    const float* b4   = (const float*)d_in[13];
    float* out = (float*)d_out;
    _Float16* wsw = (_Float16*)d_ws;

    inr_prep<<<SWTOT/256, 256, 0, stream>>>(W1, W2, W3, W4, sidx, sv, wsw, out + OUT_PIX*3);
    inr_fused<<<OUT_PIX/128, 256, 0, stream>>>(x, sidx, sv, ra, cs, csh,
                                               b1, b2, b3, b4, wsw, out);
}

// Round 6
// 149.508 us; speedup vs baseline: 1.0138x; 1.0138x over previous
//
#include <hip/hip_runtime.h>
#include <math.h>

typedef _Float16 half8  __attribute__((ext_vector_type(8)));
typedef _Float16 half2v __attribute__((ext_vector_type(2)));
typedef float    f32x4  __attribute__((ext_vector_type(4)));
typedef float    f32x2  __attribute__((ext_vector_type(2)));
typedef float    f32x16 __attribute__((ext_vector_type(16)));
typedef int      int2v  __attribute__((ext_vector_type(2)));
typedef int      int4v  __attribute__((ext_vector_type(4)));

// swizzled-weight offsets in halfs inside d_ws (32x32x16 fragment layout)
#define W1OFF 0        // 8 MT-tiles * 64 lanes * 8 = 4096 halfs (K padded 2->16)
#define W2OFF 4096     // 16 kk * 8 MT * 64 * 8 = 65536
#define W3OFF 69632    // 65536
#define W4OFF 135168   // 16x16 frags: 8 kkb * 64 * 8 = 4096 (N padded 3->16)
#define SWTOT 139264
#define OUT_PIX (16*128*128)

// ---------------- prep: swizzle weights (fp32 -> f16 frag-contiguous) + dx/dy tail ----
// 32x32x16 A-frag: lane holds A[m = MT*32 + (lane&31)][k = kk*16 + (lane>>5)*8 + j]
__global__ void inr_prep(const float* __restrict__ W1, const float* __restrict__ W2,
                         const float* __restrict__ W3, const float* __restrict__ W4,
                         const int* __restrict__ sidx, const float* __restrict__ sv,
                         _Float16* __restrict__ wsw, float* __restrict__ outtail)
{
    int tid = blockIdx.x * 256 + threadIdx.x;
    if (tid < 16) {
        int si = sidx[tid];
        outtail[tid]      = sv[2*si + 1];   // dx = shift[:,1]
        outtail[16 + tid] = sv[2*si + 0];   // dy = shift[:,0]
    }
    if (tid >= SWTOT) return;
    int kind, rel;
    if      (tid < W2OFF) { kind = 0; rel = tid; }
    else if (tid < W3OFF) { kind = 1; rel = tid - W2OFF; }
    else if (tid < W4OFF) { kind = 2; rel = tid - W3OFF; }
    else                  { kind = 3; rel = tid - W4OFF; }
    int j    = rel & 7;
    int lane = (rel >> 3) & 63;
    int blk  = rel >> 9;
    float val;
    if (kind == 3) {                       // W4 (16x16 frag): A[m][k] = W4[k][m], m<3 else 0
        int q = lane >> 4, ln = lane & 15;
        int m = ln;
        int k = blk * 32 + q * 8 + j;
        val = (m < 3) ? W4[k*3 + m] : 0.0f;
    } else {
        int hi = lane >> 5, lo = lane & 31;
        if (kind == 0) {                   // W1: one kk (K padded 2->16), blk = MT
            int m = blk*32 + lo;
            int k = hi*8 + j;
            val = (k < 2) ? W1[k*256 + m] : 0.0f;
        } else {                           // W2/W3: blk = kk*8 + MT
            int MT = blk & 7, kk = blk >> 3;
            int m = MT*32 + lo;
            int k = kk*16 + hi*8 + j;
            val = (kind == 1) ? W2[k*256 + m] : W3[k*256 + m];
        }
    }
    wsw[tid] = (_Float16)val;
}

// ---------------- fused MLP ----------------
// R2 loop structure (best measured: 72.4 us) + R5's proven conflict-free epilogue.
// LDS layout: hbuf[(hid>>3)*1024 + px*8 + (hid&7)]  (granule = 8 halfs, 128 px)
// acc C/D: lane(hi,lo) reg r = act[64w+32mt+(r&3)+8(r>>2)+4hi][32nt+lo]
// F[i][nt] (B-frag form, granule 8w+2i+hi): lane = act[64w+16i+8hi+j][32nt+lo];
//   built via 2x permlane32_swap per frag; written as b128 (stride-16B, conflict-free).

__device__ __forceinline__ int pack_relu(float a, float b)
{
    half2v hp;
    hp[0] = (_Float16)fmaxf(a, 0.f);
    hp[1] = (_Float16)fmaxf(b, 0.f);
    return __builtin_bit_cast(int, hp);
}

__device__ __forceinline__ void make_frags(const f32x16 (&acc)[2][4], half8 (&F)[4][4])
{
#pragma unroll
    for (int i = 0; i < 4; ++i) {
        int ms = i >> 1, e = i & 1;
#pragma unroll
        for (int nt = 0; nt < 4; ++nt) {
            int w0 = pack_relu(acc[ms][nt][8*e+0], acc[ms][nt][8*e+1]);
            int w1 = pack_relu(acc[ms][nt][8*e+2], acc[ms][nt][8*e+3]);
            int w2 = pack_relu(acc[ms][nt][8*e+4], acc[ms][nt][8*e+5]);
            int w3 = pack_relu(acc[ms][nt][8*e+6], acc[ms][nt][8*e+7]);
            int2v r02 = __builtin_amdgcn_permlane32_swap(w0, w2, false, false);
            int2v r13 = __builtin_amdgcn_permlane32_swap(w1, w3, false, false);
            int4v fw;
            fw[0] = r02[0];   // j0,j1
            fw[1] = r13[0];   // j2,j3
            fw[2] = r02[1];   // j4,j5
            fw[3] = r13[1];   // j6,j7
            F[i][nt] = __builtin_bit_cast(half8, fw);
        }
    }
}

// acc[mt][nt][4m+c] = bias[64w + 32mt + 8m + 4hi + c]  (bias folded into acc init)
__device__ __forceinline__ void bias_init(f32x16 (&acc)[2][4], const float* __restrict__ bias,
                                          int w, int hi)
{
#pragma unroll
    for (int mt = 0; mt < 2; ++mt)
#pragma unroll
        for (int m = 0; m < 4; ++m) {
            f32x4 bv = *(const f32x4*)&bias[64*w + 32*mt + 8*m + 4*hi];
#pragma unroll
            for (int nt = 0; nt < 4; ++nt)
#pragma unroll
                for (int c = 0; c < 4; ++c)
                    acc[mt][nt][4*m+c] = bv[c];
        }
}

// write F to own granules: 16x ds_write_b128, conflict-free (stride-16B per lane)
__device__ __forceinline__ void write_frags(_Float16* hbuf, const half8 (&F)[4][4],
                                            int w, int lane)
{
    int lo = lane & 31, hi = lane >> 5;
#pragma unroll
    for (int i = 0; i < 4; ++i)
#pragma unroll
        for (int nt = 0; nt < 4; ++nt)
            *(half8*)&hbuf[(8*w + 2*i + hi)*1024 + (32*nt + lo)*8] = F[i][nt];
}

// R2's kk loop verbatim (all 16 kk from LDS, compiler-scheduled), then
// register-only make_frags, barrier, clean write burst, barrier.
template<int NKK>
__device__ __forceinline__ void do_layer32(const half8* __restrict__ Asw,
                                           const float* __restrict__ bias,
                                           _Float16* hbuf, int w, int lane,
                                           half8 (&F)[4][4])
{
    int lo = lane & 31, hi = lane >> 5;
    f32x16 acc[2][4];
    bias_init(acc, bias, w, hi);

#pragma unroll
    for (int kk = 0; kk < NKK; ++kk) {
        half8 aw[2];                                   // weights: global dwordx4, L1/L2-hot
#pragma unroll
        for (int mt = 0; mt < 2; ++mt)
            aw[mt] = Asw[(kk*8 + 2*w + mt)*64 + lane];
        half8 bf[4];                                   // activations: ds_read_b128
        int g = kk*2 + hi;
#pragma unroll
        for (int nt = 0; nt < 4; ++nt)
            bf[nt] = *(const half8*)&hbuf[g*1024 + (32*nt + lo)*8];
#pragma unroll
        for (int nt = 0; nt < 4; ++nt)
#pragma unroll
            for (int mt = 0; mt < 2; ++mt)
                acc[mt][nt] = __builtin_amdgcn_mfma_f32_32x32x16_f16(aw[mt], bf[nt], acc[mt][nt], 0, 0, 0);
    }

    make_frags(acc, F);                    // register-only: relu + f16 pack + permlane
    __syncthreads();                       // B: all reads of hbuf done
    write_frags(hbuf, F, w, lane);         // 16x ds_write_b128, conflict-free
    __syncthreads();                       // A: writes visible to all waves
}

__launch_bounds__(256, 2)
__global__ void inr_fused(const float* __restrict__ x, const int* __restrict__ sidx_p,
                          const float* __restrict__ sv, const float* __restrict__ ra,
                          const float* __restrict__ cs, const float* __restrict__ csh,
                          const float* __restrict__ b1, const float* __restrict__ b2,
                          const float* __restrict__ b3, const float* __restrict__ b4,
                          const _Float16* __restrict__ wsw, float* __restrict__ out)
{
    __shared__ __align__(16) _Float16 hbuf[32768];     // 128 px x 256 hid, 64 KB
    int t = threadIdx.x;
    int lane = t & 63, w = t >> 6, q = lane >> 4, ln = lane & 15;
    int pixbase = blockIdx.x * 128;
    int b = pixbase >> 14;                             // 16384 px per image
    int sidx = sidx_p[b];
    float dy = sv[2*sidx], dx = sv[2*sidx + 1];
    float ang = ra[sidx];
    float sn, cn;
    sincosf(ang, &sn, &cn);

    // stage coords: layer-1 K=16 -> granules 0,1 only; uv at hid 0,1
    if (t < 128) {
        int p = t;
        f32x2 xv = *(const f32x2*)&x[(pixbase + p)*2];
        float u = cn*xv[0] - sn*xv[1] + dx;
        float v = sn*xv[0] + cn*xv[1] + dy;
        half8 z;
#pragma unroll
        for (int i = 0; i < 8; ++i) z[i] = (_Float16)0.0f;
        z[0] = (_Float16)u; z[1] = (_Float16)v;
        *(half8*)&hbuf[0*1024 + p*8] = z;
    } else {
        int p = t - 128;
        half8 z;
#pragma unroll
        for (int i = 0; i < 8; ++i) z[i] = (_Float16)0.0f;
        *(half8*)&hbuf[1*1024 + p*8] = z;
    }
    __syncthreads();                                   // sync0: input staged

    const half8* wsw8 = (const half8*)wsw;
    half8 F[4][4];
    do_layer32<1>(wsw8,                 b1, hbuf, w, lane, F);   // layer 1 (K=16 padded)
    do_layer32<16>(wsw8 + (W2OFF >> 3), b2, hbuf, w, lane, F);   // layer 2
    do_layer32<16>(wsw8 + (W3OFF >> 3), b3, hbuf, w, lane, F);   // layer 3

    // layer 4: 16x16 (M=16, 3 real), each wave -> 32 pixels
    const half8* w4p = wsw8 + (W4OFF >> 3);
    f32x4 a4[2];
    a4[0] = (f32x4){0.f,0.f,0.f,0.f};
    a4[1] = (f32x4){0.f,0.f,0.f,0.f};
#pragma unroll
    for (int kkb = 0; kkb < 8; ++kkb) {
        half8 aw = w4p[kkb*64 + lane];
#pragma unroll
        for (int i = 0; i < 2; ++i) {
            int pixel = 16*(2*w + i) + ln;
            half8 bf = *(const half8*)&hbuf[(kkb*4 + q)*1024 + pixel*8];
            a4[i] = __builtin_amdgcn_mfma_f32_16x16x32_f16(aw, bf, a4[i], 0, 0, 0);
        }
    }
    if (q == 0) {                                      // rows 0..2 = output channels
        bool doc = (sidx != 0);
        float s0 = cs[sidx*3+0], s1 = cs[sidx*3+1], s2 = cs[sidx*3+2];
        float t0 = csh[sidx*3+0], t1 = csh[sidx*3+1], t2 = csh[sidx*3+2];
        float bb0 = b4[0], bb1 = b4[1], bb2 = b4[2];
#pragma unroll
        for (int i = 0; i < 2; ++i) {
            int gp = pixbase + 16*(2*w + i) + ln;
            float v0 = a4[i][0] + bb0;
            float v1 = a4[i][1] + bb1;
            float v2 = a4[i][2] + bb2;
            if (doc) { v0 = v0*s0 + t0; v1 = v1*s1 + t1; v2 = v2*s2 + t2; }
            out[gp*3 + 0] = v0;
            out[gp*3 + 1] = v1;
            out[gp*3 + 2] = v2;
        }
    }
}

extern "C" void kernel_launch(void* const* d_in, const int* in_sizes, int n_in,
                              void* d_out, int out_size, void* d_ws, size_t ws_size,
                              hipStream_t stream)
{
    const float* x    = (const float*)d_in[0];
    const int*   sidx = (const int*)  d_in[1];
    const float* sv   = (const float*)d_in[2];
    const float* ra   = (const float*)d_in[3];
    const float* cs   = (const float*)d_in[4];
    const float* csh  = (const float*)d_in[5];
    const float* W1   = (const float*)d_in[6];
    const float* b1   = (const float*)d_in[7];
    const float* W2   = (const float*)d_in[8];
    const float* b2   = (const float*)d_in[9];
    const float* W3   = (const float*)d_in[10];
    const float* b3   = (const float*)d_in[11];
    const float* W4   = (const float*)d_in[12];
    const float* b4   = (const float*)d_in[13];
    float* out = (float*)d_out;
    _Float16* wsw = (_Float16*)d_ws;

    inr_prep<<<SWTOT/256, 256, 0, stream>>>(W1, W2, W3, W4, sidx, sv, wsw, out + OUT_PIX*3);
    inr_fused<<<OUT_PIX/128, 256, 0, stream>>>(x, sidx, sv, ra, cs, csh,
                                               b1, b2, b3, b4, wsw, out);
}

// Round 9
// 143.895 us; speedup vs baseline: 1.0534x; 1.0390x over previous
//
#include <hip/hip_runtime.h>
#include <math.h>

typedef _Float16 half8  __attribute__((ext_vector_type(8)));
typedef _Float16 half4v __attribute__((ext_vector_type(4)));
typedef _Float16 half2v __attribute__((ext_vector_type(2)));
typedef float    f32x4  __attribute__((ext_vector_type(4)));

// swizzled-weight offsets in halfs inside d_ws
#define W1OFF 0        // 16 MT-tiles * 64 lanes * 8 = 8192 halfs (K padded 2->32)
#define W2OFF 8192     // 8 kkb * 16 MT * 64 * 8 = 65536
#define W3OFF 73728    // 65536
#define W4OFF 139264   // 8 kkb * 64 * 8 = 4096 (N padded 3->16)
#define SWTOT 143360
#define OUT_PIX (16*128*128)

// ---------------- prep: swizzle weights (fp32 -> f16 frag-contiguous) + dx/dy tail ----
__global__ void inr_prep(const float* __restrict__ W1, const float* __restrict__ W2,
                         const float* __restrict__ W3, const float* __restrict__ W4,
                         const int* __restrict__ sidx, const float* __restrict__ sv,
                         _Float16* __restrict__ wsw, float* __restrict__ outtail)
{
    int tid = blockIdx.x * 256 + threadIdx.x;
    if (tid < 16) {
        int si = sidx[tid];
        outtail[tid]      = sv[2*si + 1];   // dx = shift[:,1]
        outtail[16 + tid] = sv[2*si + 0];   // dy = shift[:,0]
    }
    if (tid >= SWTOT) return;
    int kind, rel;
    if      (tid < W2OFF) { kind = 0; rel = tid; }
    else if (tid < W3OFF) { kind = 1; rel = tid - W2OFF; }
    else if (tid < W4OFF) { kind = 2; rel = tid - W3OFF; }
    else                  { kind = 3; rel = tid - W4OFF; }
    int j    = rel & 7;
    int lane = (rel >> 3) & 63;
    int blk  = rel >> 9;
    int q = lane >> 4, ln = lane & 15;
    float val;
    if (kind == 3) {                       // W4: A[m][k] = W4[k][m], m<3 else 0
        int m = ln;
        int k = blk * 32 + q * 8 + j;
        val = (m < 3) ? W4[k*3 + m] : 0.0f;
    } else {
        int MT = blk & 15, kkb = blk >> 4;
        int m = MT*16 + ln;
        int k = kkb*32 + q*8 + j;
        if      (kind == 0) val = (k < 2) ? W1[k*256 + m] : 0.0f;
        else if (kind == 1) val = W2[k*256 + m];
        else                val = W3[k*256 + m];
    }
    wsw[tid] = (_Float16)val;
}

// ---------------- fused MLP ----------------
// LDS activation layout: granule-major.  Element (pixel, hid) lives at
//   hbuf[(hid>>3)*1024 + pixel*8 + (hid&7)]     (granule = 8 halfs = 16 B, 128 px)
template<int NKK>
__device__ __forceinline__ void do_layer(const half8* __restrict__ Asw,
                                         const float* __restrict__ bias,
                                         _Float16* hbuf, int w, int q, int ln, int lane)
{
    f32x4 acc[4][8];
#pragma unroll
    for (int mt = 0; mt < 4; ++mt)
#pragma unroll
        for (int nt = 0; nt < 8; ++nt)
            acc[mt][nt] = (f32x4){0.f, 0.f, 0.f, 0.f};

#pragma unroll
    for (int kkb = 0; kkb < NKK; ++kkb) {
        half8 aw[4];                                   // weights: global dwordx4, L2-hot
#pragma unroll
        for (int mt = 0; mt < 4; ++mt)
            aw[mt] = Asw[(kkb*16 + 4*w + mt)*64 + lane];
        half8 bf[8];                                   // activations: ds_read_b128, stride-16B
        int g = kkb*4 + q;
#pragma unroll
        for (int nt = 0; nt < 8; ++nt)
            bf[nt] = *(const half8*)&hbuf[g*1024 + (16*nt + ln)*8];
#pragma unroll
        for (int nt = 0; nt < 8; ++nt)
#pragma unroll
            for (int mt = 0; mt < 4; ++mt)
                acc[mt][nt] = __builtin_amdgcn_mfma_f32_16x16x32_f16(aw[mt], bf[nt], acc[mt][nt], 0, 0, 0);
    }
    __syncthreads();                                   // all reads of hbuf done
    // epilogue: bias + relu + f16 cast; lane holds 4 consecutive hids -> one b64 write
#pragma unroll
    for (int mt = 0; mt < 4; ++mt) {
        int hid0 = 64*w + 16*mt + 4*q;
        f32x4 bv = *(const f32x4*)&bias[hid0];
        int g = hid0 >> 3;
        int o = hid0 & 7;
#pragma unroll
        for (int nt = 0; nt < 8; ++nt) {
            int pixel = 16*nt + ln;
            f32x4 a = acc[mt][nt];
            half4v hv;
            hv[0] = (_Float16)fmaxf(a[0] + bv[0], 0.f);
            hv[1] = (_Float16)fmaxf(a[1] + bv[1], 0.f);
            hv[2] = (_Float16)fmaxf(a[2] + bv[2], 0.f);
            hv[3] = (_Float16)fmaxf(a[3] + bv[3], 0.f);
            *(half4v*)&hbuf[g*1024 + pixel*8 + o] = hv;
        }
    }
    __syncthreads();
}

__launch_bounds__(256, 2)
__global__ void inr_fused(const float* __restrict__ x, const int* __restrict__ sidx_p,
                          const float* __restrict__ sv, const float* __restrict__ ra,
                          const float* __restrict__ cs, const float* __restrict__ csh,
                          const float* __restrict__ b1, const float* __restrict__ b2,
                          const float* __restrict__ b3, const float* __restrict__ b4,
                          const _Float16* __restrict__ wsw, float* __restrict__ out)
{
    __shared__ __align__(16) _Float16 hbuf[32768];     // 128 px x 256 hid, 64 KB
    int t = threadIdx.x;
    int lane = t & 63, w = t >> 6, q = lane >> 4, ln = lane & 15;
    int pixbase = blockIdx.x * 128;
    int b = pixbase >> 14;                             // 16384 px per image
    int sidx = sidx_p[b];
    float dy = sv[2*sidx], dx = sv[2*sidx + 1];
    float ang = ra[sidx];
    float sn, cn;
    sincosf(ang, &sn, &cn);

    // stage coords: hids 0..31 (granules 0..3), zero-padded K, uv at hid 0,1
    if (t < 128) {
        int p = t;
        float x0 = x[(pixbase + p)*2 + 0];
        float x1 = x[(pixbase + p)*2 + 1];
        float u = cn*x0 - sn*x1 + dx;
        float v = sn*x0 + cn*x1 + dy;
        half8 z;
#pragma unroll
        for (int i = 0; i < 8; ++i) z[i] = (_Float16)0.0f;
#pragma unroll
        for (int g = 1; g < 4; ++g)
            *(half8*)&hbuf[g*1024 + p*8] = z;
        z[0] = (_Float16)u; z[1] = (_Float16)v;
        *(half8*)&hbuf[0*1024 + p*8] = z;
    }
    __syncthreads();

    const half8* wsw8 = (const half8*)wsw;
    do_layer<1>(wsw8,                b1, hbuf, w, q, ln, lane);   // layer 1 (K=32 padded)
    do_layer<8>(wsw8 + (W2OFF >> 3), b2, hbuf, w, q, ln, lane);   // layer 2
    do_layer<8>(wsw8 + (W3OFF >> 3), b3, hbuf, w, q, ln, lane);   // layer 3

    // layer 4: M=16 (3 real), each wave -> 32 pixels
    const half8* w4p = wsw8 + (W4OFF >> 3);
    f32x4 a4[2];
    a4[0] = (f32x4){0.f,0.f,0.f,0.f};
    a4[1] = (f32x4){0.f,0.f,0.f,0.f};
#pragma unroll
    for (int kkb = 0; kkb < 8; ++kkb) {
        half8 aw = w4p[kkb*64 + lane];
#pragma unroll
        for (int i = 0; i < 2; ++i) {
            int pixel = 16*(2*w + i) + ln;
            half8 bf = *(const half8*)&hbuf[(kkb*4 + q)*1024 + pixel*8];
            a4[i] = __builtin_amdgcn_mfma_f32_16x16x32_f16(aw, bf, a4[i], 0, 0, 0);
        }
    }
    if (q == 0) {                                      // rows 0..2 = output channels
        bool doc = (sidx != 0);
        float s0 = cs[sidx*3+0], s1 = cs[sidx*3+1], s2 = cs[sidx*3+2];
        float t0 = csh[sidx*3+0], t1 = csh[sidx*3+1], t2 = csh[sidx*3+2];
        float bb0 = b4[0], bb1 = b4[1], bb2 = b4[2];
#pragma unroll
        for (int i = 0; i < 2; ++i) {
            int gp = pixbase + 16*(2*w + i) + ln;
            float v0 = a4[i][0] + bb0;
            float v1 = a4[i][1] + bb1;
            float v2 = a4[i][2] + bb2;
            if (doc) { v0 = v0*s0 + t0; v1 = v1*s1 + t1; v2 = v2*s2 + t2; }
            out[gp*3 + 0] = v0;
            out[gp*3 + 1] = v1;
            out[gp*3 + 2] = v2;
        }
    }
}

extern "C" void kernel_launch(void* const* d_in, const int* in_sizes, int n_in,
                              void* d_out, int out_size, void* d_ws, size_t ws_size,
                              hipStream_t stream)
{
    const float* x    = (const float*)d_in[0];
    const int*   sidx = (const int*)  d_in[1];
    const float* sv   = (const float*)d_in[2];
    const float* ra   = (const float*)d_in[3];
    const float* cs   = (const float*)d_in[4];
    const float* csh  = (const float*)d_in[5];
    const float* W1   = (const float*)d_in[6];
    const float* b1   = (const float*)d_in[7];
    const float* W2   = (const float*)d_in[8];
    const float* b2   = (const float*)d_in[9];
    const float* W3   = (const float*)d_in[10];
    const float* b3   = (const float*)d_in[11];
    const float* W4   = (const float*)d_in[12];
    const float* b4   = (const float*)d_in[13];
    float* out = (float*)d_out;
    _Float16* wsw = (_Float16*)d_ws;

    inr_prep<<<SWTOT/256, 256, 0, stream>>>(W1, W2, W3, W4, sidx, sv, wsw, out + OUT_PIX*3);
    inr_fused<<<OUT_PIX/128, 256, 0, stream>>>(x, sidx, sv, ra, cs, csh,
                                               b1, b2, b3, b4, wsw, out);
}